// Round 5
// baseline (409.308 us; speedup 1.0000x reference)
//
#include <hip/hip_runtime.h>

#define DM 256
#define NOUT 768
#define JOINTS 22
#define MROWS 88            // 4 frames per block (88 % 22 == 0)
#define NBLK 1024           // 90112 / 88

typedef __attribute__((ext_vector_type(8))) short bf16x8;
typedef __attribute__((ext_vector_type(4))) float f32x4;

__device__ __forceinline__ float b2f(unsigned short u) {
    union { unsigned int i; float f; } x; x.i = ((unsigned int)u) << 16; return x.f;
}
__device__ __forceinline__ unsigned short f2b(float f) {
    union { float f; unsigned int u; } x; x.f = f;
    unsigned int r = x.u + 0x7FFFu + ((x.u >> 16) & 1u);
    return (unsigned short)(r >> 16);
}

// ws layout
#define OFF_PEWB 0
#define OFF_WCAN (JOINTS * NOUT * 4)                 // 67584

// ---------------- convert W (fp32 -> bf16), 3 matrices ----------------
__global__ __launch_bounds__(256) void wconv_kernel(const float* __restrict__ w0,
                                                    const float* __restrict__ w1,
                                                    const float* __restrict__ w2,
                                                    unsigned short* __restrict__ wcan)
{
    const float* w = (blockIdx.y == 0) ? w0 : (blockIdx.y == 1 ? w1 : w2);
    int i = (blockIdx.x * 256 + threadIdx.x) * 8;
    const float* s = w + i;
    union { uint4 v; float f[4]; } a, b;
    a.v = *(const uint4*)(s);
    b.v = *(const uint4*)(s + 4);
    union { uint4 v; unsigned short u[8]; } o;
    #pragma unroll
    for (int k = 0; k < 4; ++k) { o.u[k] = f2b(a.f[k]); o.u[4 + k] = f2b(b.f[k]); }
    *(uint4*)(wcan + blockIdx.y * (DM * DM) + i) = o.v;
}

// ---------------- PEWB[j,e] = bias[e] + sum_d pe[j,d] * W[e,d]  (fp32) ----------------
__global__ __launch_bounds__(256) void pewb_kernel(const float* __restrict__ wq,
                                                   const float* __restrict__ wk,
                                                   const float* __restrict__ wv,
                                                   const float* __restrict__ bq,
                                                   const float* __restrict__ bk,
                                                   const float* __restrict__ bv,
                                                   float* __restrict__ pewb)
{
    __shared__ float pe_s[DM];
    const int j   = blockIdx.x / 3;
    const int mat = blockIdx.x % 3;
    const int t = threadIdx.x;
    {
        int i = t >> 1;
        float div = __expf((float)(2 * i) * (-9.210340371976184f / 256.0f)); // -ln(10000)/256
        float ang = (float)j * div;
        pe_s[t] = (t & 1) ? cosf(ang) : sinf(ang);
    }
    __syncthreads();
    const float* w  = (mat == 0) ? wq : (mat == 1 ? wk : wv);
    const float* bb = (mat == 0) ? bq : (mat == 1 ? bk : bv);
    float acc = bb[t];
    const float* wr = w + (size_t)t * DM;
    #pragma unroll 8
    for (int d = 0; d < DM; ++d) acc += pe_s[d] * wr[d];
    pewb[j * NOUT + mat * DM + t] = acc;
}

// ---------------- fused QKV-GEMM + MFMA block-diagonal attention ----------------
// One block = 88 tokens (4 frames). Per iter (2 heads): MFMA GEMM (96x192x256) ->
// epilogue (+PEWB, Q pre-scaled by 1/sqrt(32)) writes Q,K (row-major, stride 32)
// and V^T ([hl][fr][d][k], stride 24, k-pad zeroed once) to LDS -> each wave owns
// one (frame, head): S^T = mfma(K,Q), in-reg masked softmax (2 shfl_xor quad
// reduce), P repacked to bf16 A-frags via 16 shfls, O = mfma(P, V^T), store f32.
// LDS total 79888 B -> 2 blocks/CU (the 81920-B version fit only 1: occ 22.7%).
__global__ __launch_bounds__(512, 2) void fused_kernel(const float* __restrict__ x,
                                                       const unsigned short* __restrict__ wcan,
                                                       const float* __restrict__ pewb,
                                                       float* __restrict__ out)
{
    __shared__ __align__(16) unsigned short xs[MROWS * 256];         // 45056 B, chunk-swizzled
    __shared__ __align__(16) unsigned short q_s[2 * MROWS * 32];     // 11264 B
    __shared__ __align__(16) unsigned short k_s[2 * MROWS * 32];     // 11264 B
    __shared__ __align__(16) unsigned short v_t[2 * 4 * 32 * 24 + 8];// 12304 B (pad for b128 tail)

    const int t    = threadIdx.x;
    const int tok0 = blockIdx.x * MROWS;

    // ---- stage x tile fp32 -> bf16, swizzled (chunk c at (c&24)|((c&7)^(row&7))) ----
    for (int i = t; i < MROWS * 32; i += 512) {
        int row = i >> 5, c = i & 31;
        const float* src = x + (size_t)(tok0 + row) * DM + c * 8;
        union { uint4 v; float f[4]; } a, b;
        a.v = *(const uint4*)(src);
        b.v = *(const uint4*)(src + 4);
        union { uint4 v; unsigned short u[8]; } o;
        #pragma unroll
        for (int k = 0; k < 4; ++k) { o.u[k] = f2b(a.f[k]); o.u[4 + k] = f2b(b.f[k]); }
        int cs = (c & 24) | ((c & 7) ^ (row & 7));
        *(uint4*)(&xs[row * 256 + cs * 8]) = o.v;
    }
    // one-time zero of v_t (k-pad lanes 22/23 are never written by the epilogue)
    {
        unsigned int* vz = (unsigned int*)v_t;
        for (int i = t; i < (2 * 4 * 32 * 24 + 8) / 2; i += 512) vz[i] = 0u;
    }
    __syncthreads();

    const int lane = t & 63;
    const int wave = t >> 6;
    const int wm   = (wave & 1) * 48;      // M wave-group: rows [wm, wm+48)
    const int wn   = (wave >> 1) * 48;     // N wave-group: cols [wn, wn+48) of 192
    const int lrow = lane & 15;
    const int quad = lane >> 4;

    // A-fragment row indices (M padded 88->96: clamp, results masked at store)
    int abase[3], axor[3];
    #pragma unroll
    for (int mi = 0; mi < 3; ++mi) {
        int ar = wm + mi * 16 + lrow;
        if (ar > MROWS - 1) ar = MROWS - 1;
        abase[mi] = ar * 256;
        axor[mi]  = ar & 7;
    }

    #pragma unroll 1
    for (int it = 0; it < 4; ++it) {
        const int h0 = it * 2;

        // B row pointers: col n of this iter -> W row. n: mat=n>>6, hl=(n>>5)&1, d=n&31
        const unsigned short* bp[3];
        #pragma unroll
        for (int ni = 0; ni < 3; ++ni) {
            int n   = wn + ni * 16 + lrow;
            int mat = n >> 6;
            int e   = (h0 + ((n >> 5) & 1)) * 32 + (n & 31);
            bp[ni] = wcan + mat * (DM * DM) + (size_t)e * DM + quad * 8;
        }

        f32x4 acc[3][3];
        #pragma unroll
        for (int mi = 0; mi < 3; ++mi)
            #pragma unroll
            for (int ni = 0; ni < 3; ++ni)
                acc[mi][ni] = (f32x4){0.f, 0.f, 0.f, 0.f};

        auto kstep = [&](int kk, bf16x8* breg) {
            bf16x8 a[3];
            int c = (kk >> 3) + quad;
            #pragma unroll
            for (int mi = 0; mi < 3; ++mi) {
                int cs = (c & 24) | ((c & 7) ^ axor[mi]);
                a[mi] = *(const bf16x8*)(&xs[abase[mi] + cs * 8]);
            }
            #pragma unroll
            for (int mi = 0; mi < 3; ++mi)
                #pragma unroll
                for (int ni = 0; ni < 3; ++ni)
                    acc[mi][ni] = __builtin_amdgcn_mfma_f32_16x16x32_bf16(
                        a[mi], breg[ni], acc[mi][ni], 0, 0, 0);
        };

        bf16x8 bA[3], bB[3];
        #pragma unroll
        for (int ni = 0; ni < 3; ++ni) bA[ni] = *(const bf16x8*)(bp[ni]);
        #pragma unroll 1
        for (int kk = 0; kk < 192; kk += 64) {
            #pragma unroll
            for (int ni = 0; ni < 3; ++ni) bB[ni] = *(const bf16x8*)(bp[ni] + kk + 32);
            kstep(kk, bA);
            #pragma unroll
            for (int ni = 0; ni < 3; ++ni) bA[ni] = *(const bf16x8*)(bp[ni] + kk + 64);
            kstep(kk + 32, bB);
        }
        #pragma unroll
        for (int ni = 0; ni < 3; ++ni) bB[ni] = *(const bf16x8*)(bp[ni] + 224);
        kstep(192, bA);
        kstep(224, bB);

        __syncthreads();   // previous iter's attn readers are done with q/k/v LDS

        // ---- epilogue: + PEWB[joint]; Q scaled by 1/sqrt(32); V stored transposed ----
        #pragma unroll
        for (int ni = 0; ni < 3; ++ni) {
            int n   = wn + ni * 16 + lrow;
            int mat = n >> 6;            // wave-uniform (16-aligned slices)
            int hl2 = (n >> 5) & 1;
            int d   = n & 31;
            int pcol = mat * 256 + (h0 + hl2) * 32 + d;
            #pragma unroll
            for (int mi = 0; mi < 3; ++mi) {
                int rbase = wm + mi * 16 + quad * 4;   // C row = quad*4 + reg
                if (rbase < MROWS) {
                    #pragma unroll
                    for (int rg = 0; rg < 4; ++rg) {
                        int r = rbase + rg;
                        int joint = r % 22;            // tok0 % 22 == 0
                        float val = acc[mi][ni][rg] + pewb[joint * NOUT + pcol];
                        if (mat == 0) {
                            q_s[(hl2 * MROWS + r) * 32 + d] = f2b(val * 0.17677669529663688f);
                        } else if (mat == 1) {
                            k_s[(hl2 * MROWS + r) * 32 + d] = f2b(val);
                        } else {
                            int frr = r / 22;
                            v_t[((hl2 * 4 + frr) * 32 + d) * 24 + joint] = f2b(val);
                        }
                    }
                }
            }
        }
        __syncthreads();

        // ---- MFMA attention: wave = (frame, local head) ----
        {
            const int fr2  = wave >> 1;
            const int hl2  = wave & 1;
            const int rowb = hl2 * MROWS + fr2 * 22;

            // S^T[k,q] = sum_d K[k,d] Q[q,d]: A = K rows, B = Q rows (both lrow-indexed)
            bf16x8 ka[2], qb[2];
            #pragma unroll
            for (int km = 0; km < 2; ++km) {
                int kr = km * 16 + lrow; if (kr > 21) kr = 21;
                ka[km] = *(const bf16x8*)(&k_s[(rowb + kr) * 32 + quad * 8]);
            }
            #pragma unroll
            for (int qn = 0; qn < 2; ++qn) {
                int qr = qn * 16 + lrow; if (qr > 21) qr = 21;
                qb[qn] = *(const bf16x8*)(&q_s[(rowb + qr) * 32 + quad * 8]);
            }
            f32x4 st[2][2];
            #pragma unroll
            for (int km = 0; km < 2; ++km)
                #pragma unroll
                for (int qn = 0; qn < 2; ++qn)
                    st[km][qn] = __builtin_amdgcn_mfma_f32_16x16x32_bf16(
                        ka[km], qb[qn], (f32x4){0.f, 0.f, 0.f, 0.f}, 0, 0, 0);

            // softmax per q (= lrow of each qn tile); lane holds k = quad*4+r (+16)
            unsigned int u[2][2][2];   // [qn][km][rpair] packed bf16 pairs of P
            #pragma unroll
            for (int qn = 0; qn < 2; ++qn) {
                float mx = -3.0e38f;
                #pragma unroll
                for (int r2 = 0; r2 < 4; ++r2) mx = fmaxf(mx, st[0][qn][r2]);
                #pragma unroll
                for (int r2 = 0; r2 < 4; ++r2)
                    if (16 + quad * 4 + r2 < 22) mx = fmaxf(mx, st[1][qn][r2]);
                mx = fmaxf(mx, __shfl_xor(mx, 16));
                mx = fmaxf(mx, __shfl_xor(mx, 32));
                float p0[4], p1[4];
                float sum = 0.f;
                #pragma unroll
                for (int r2 = 0; r2 < 4; ++r2) { p0[r2] = __expf(st[0][qn][r2] - mx); sum += p0[r2]; }
                #pragma unroll
                for (int r2 = 0; r2 < 4; ++r2) {
                    float e = (16 + quad * 4 + r2 < 22) ? __expf(st[1][qn][r2] - mx) : 0.f;
                    p1[r2] = e; sum += e;
                }
                sum += __shfl_xor(sum, 16);
                sum += __shfl_xor(sum, 32);
                float inv = 1.f / sum;
                #pragma unroll
                for (int r2 = 0; r2 < 4; ++r2) { p0[r2] *= inv; p1[r2] *= inv; }
                u[qn][0][0] = (unsigned int)f2b(p0[0]) | ((unsigned int)f2b(p0[1]) << 16);
                u[qn][0][1] = (unsigned int)f2b(p0[2]) | ((unsigned int)f2b(p0[3]) << 16);
                u[qn][1][0] = (unsigned int)f2b(p1[0]) | ((unsigned int)f2b(p1[1]) << 16);
                u[qn][1][1] = (unsigned int)f2b(p1[2]) | ((unsigned int)f2b(p1[3]) << 16);
            }

            // repack P (C layout) -> A-frag layout: target k = quad*8 + 2j + {0,1};
            // source lane = lrow + 16*((quad&1)*2 + (j>>1)), km = quad>>1, rp = j&1.
            bf16x8 pa[2];
            #pragma unroll
            for (int qm = 0; qm < 2; ++qm) {
                union { bf16x8 v; unsigned int w[4]; } au;
                #pragma unroll
                for (int j = 0; j < 4; ++j) {
                    int src = lrow + 16 * ((quad & 1) * 2 + (j >> 1));
                    unsigned int lo = (unsigned int)__shfl((int)u[qm][0][j & 1], src, 64);
                    unsigned int hi = (unsigned int)__shfl((int)u[qm][1][j & 1], src, 64);
                    au.w[j] = (quad < 2) ? lo : hi;
                }
                pa[qm] = au.v;
            }

            // O[q,d] = P x V: B-frag from V^T rows (d = lrow), k = quad*8+e (pad reads
            // land in the zeroed stride-24 tail / next rows; P there is exactly 0)
            bf16x8 vb[2];
            #pragma unroll
            for (int dn = 0; dn < 2; ++dn)
                vb[dn] = *(const bf16x8*)(&v_t[((hl2 * 4 + fr2) * 32 + dn * 16 + lrow) * 24 + quad * 8]);

            f32x4 ot[2][2];
            #pragma unroll
            for (int qm = 0; qm < 2; ++qm)
                #pragma unroll
                for (int dn = 0; dn < 2; ++dn)
                    ot[qm][dn] = __builtin_amdgcn_mfma_f32_16x16x32_bf16(
                        pa[qm], vb[dn], (f32x4){0.f, 0.f, 0.f, 0.f}, 0, 0, 0);

            #pragma unroll
            for (int qm = 0; qm < 2; ++qm) {
                #pragma unroll
                for (int r2 = 0; r2 < 4; ++r2) {
                    int q = qm * 16 + quad * 4 + r2;
                    if (q < 22) {
                        float* op = out + (size_t)(tok0 + fr2 * 22 + q) * DM + (h0 + hl2) * 32;
                        op[lrow]      = ot[qm][0][r2];
                        op[16 + lrow] = ot[qm][1][r2];
                    }
                }
            }
        }
        // no barrier here: next iter's pre-epilogue barrier protects q/k/v/v_t.
    }
}

extern "C" void kernel_launch(void* const* d_in, const int* in_sizes, int n_in,
                              void* d_out, int out_size, void* d_ws, size_t ws_size,
                              hipStream_t stream) {
    const float* x  = (const float*)d_in[0];
    const float* wq = (const float*)d_in[1];
    const float* bq = (const float*)d_in[2];
    const float* wk = (const float*)d_in[3];
    const float* bk = (const float*)d_in[4];
    const float* wv = (const float*)d_in[5];
    const float* bv = (const float*)d_in[6];

    char* ws = (char*)d_ws;
    float*          pewb = (float*)(ws + OFF_PEWB);
    unsigned short* wcan = (unsigned short*)(ws + OFF_WCAN);

    wconv_kernel<<<dim3(32, 3), dim3(256), 0, stream>>>(wq, wk, wv, wcan);
    pewb_kernel<<<dim3(66), dim3(256), 0, stream>>>(wq, wk, wv, bq, bk, bv, pewb);
    fused_kernel<<<dim3(NBLK), dim3(512), 0, stream>>>(x, wcan, pewb, (float*)d_out);
}